// Round 1
// baseline (316.830 us; speedup 1.0000x reference)
//
#include <hip/hip_runtime.h>
#include <hip/hip_cooperative_groups.h>
#include <hip/hip_bf16.h>
#include <math.h>

namespace cg = cooperative_groups;

#define B_ 2
#define N_ 6
#define C_ 80
#define FH_ 16
#define FW_ 44
#define D_ 112
#define NX_ 128
#define NY_ 128
#define NCOL (B_ * N_ * FH_ * FW_)  /* 8448 */
#define NCELL (B_ * NY_ * NX_)      /* 32768 */
#define MAXT (NCOL * D_)            /* 946176 tuple capacity */
#define GB_CELLS 16                 /* cells per gather block (1 wave each) */
#define NCHUNK (NCELL / 64)         /* 512 scan chunks */

typedef __hip_bfloat16 bf16;
typedef unsigned short u16;

__device__ __forceinline__ float loadf(const void* p, int i, int isbf) {
  if (isbf) return __bfloat162float(((const bf16*)p)[i]);
  return ((const float*)p)[i];
}

// ---------- adjugate 4x4 inverse: static indexing only (no scratch!) ----------
__device__ void inv4(const float m[16], float invOut[16]) {
  float inv[16];
  inv[0]  =  m[5]*m[10]*m[15] - m[5]*m[11]*m[14] - m[9]*m[6]*m[15] + m[9]*m[7]*m[14] + m[13]*m[6]*m[11] - m[13]*m[7]*m[10];
  inv[4]  = -m[4]*m[10]*m[15] + m[4]*m[11]*m[14] + m[8]*m[6]*m[15] - m[8]*m[7]*m[14] - m[12]*m[6]*m[11] + m[12]*m[7]*m[10];
  inv[8]  =  m[4]*m[9]*m[15]  - m[4]*m[11]*m[13] - m[8]*m[5]*m[15] + m[8]*m[7]*m[13] + m[12]*m[5]*m[11] - m[12]*m[7]*m[9];
  inv[12] = -m[4]*m[9]*m[14]  + m[4]*m[10]*m[13] + m[8]*m[5]*m[14] - m[8]*m[6]*m[13] - m[12]*m[5]*m[10] + m[12]*m[6]*m[9];
  inv[1]  = -m[1]*m[10]*m[15] + m[1]*m[11]*m[14] + m[9]*m[2]*m[15] - m[9]*m[3]*m[14] - m[13]*m[2]*m[11] + m[13]*m[3]*m[10];
  inv[5]  =  m[0]*m[10]*m[15] - m[0]*m[11]*m[14] - m[8]*m[2]*m[15] + m[8]*m[3]*m[14] + m[12]*m[2]*m[11] - m[12]*m[3]*m[10];
  inv[9]  = -m[0]*m[9]*m[15]  + m[0]*m[11]*m[13] + m[8]*m[1]*m[15] - m[8]*m[3]*m[13] - m[12]*m[1]*m[11] + m[12]*m[3]*m[9];
  inv[13] =  m[0]*m[9]*m[14]  - m[0]*m[10]*m[13] - m[8]*m[1]*m[14] + m[8]*m[2]*m[13] + m[12]*m[1]*m[10] - m[12]*m[2]*m[9];
  inv[2]  =  m[1]*m[6]*m[15]  - m[1]*m[7]*m[14]  - m[5]*m[2]*m[15] + m[5]*m[3]*m[14] + m[13]*m[2]*m[7]  - m[13]*m[3]*m[6];
  inv[6]  = -m[0]*m[6]*m[15]  + m[0]*m[7]*m[14]  + m[4]*m[2]*m[15] - m[4]*m[3]*m[14] - m[12]*m[2]*m[7]  + m[12]*m[3]*m[6];
  inv[10] =  m[0]*m[5]*m[15]  - m[0]*m[7]*m[13]  - m[4]*m[1]*m[15] + m[4]*m[3]*m[13] + m[12]*m[1]*m[7]  - m[12]*m[3]*m[5];
  inv[14] = -m[0]*m[5]*m[14]  + m[0]*m[6]*m[13]  + m[4]*m[1]*m[14] - m[4]*m[2]*m[13] - m[12]*m[1]*m[6]  + m[12]*m[2]*m[5];
  inv[3]  = -m[1]*m[6]*m[11]  + m[1]*m[7]*m[10]  + m[5]*m[2]*m[11] - m[5]*m[3]*m[10] - m[9]*m[2]*m[7]   + m[9]*m[3]*m[6];
  inv[7]  =  m[0]*m[6]*m[11]  - m[0]*m[7]*m[10]  - m[4]*m[2]*m[11] + m[4]*m[3]*m[10] + m[8]*m[2]*m[7]   - m[8]*m[3]*m[6];
  inv[11] = -m[0]*m[5]*m[11]  + m[0]*m[7]*m[9]   + m[4]*m[1]*m[11] - m[4]*m[3]*m[9]  - m[8]*m[1]*m[7]   + m[8]*m[3]*m[5];
  inv[15] =  m[0]*m[5]*m[10]  - m[0]*m[6]*m[9]   - m[4]*m[1]*m[10] + m[4]*m[2]*m[9]  + m[8]*m[1]*m[6]   - m[8]*m[2]*m[5];
  float det = m[0]*inv[0] + m[1]*inv[4] + m[2]*inv[8] + m[3]*inv[12];
  det = 1.0f / det;
  for (int i = 0; i < 16; i++) invOut[i] = inv[i] * det;
}

__device__ void mul4(const float A[16], const float Bm[16], float Cm[16]) {
  for (int i = 0; i < 4; i++)
    for (int j = 0; j < 4; j++) {
      float s = 0.f;
      for (int k = 0; k < 4; k++) s += A[i * 4 + k] * Bm[k * 4 + j];
      Cm[i * 4 + j] = s;
    }
}

// ---------- shared geometry: voxel cell for (col, depth bin) ----------
__device__ __forceinline__ int geom_cell(const float* __restrict__ mats,
                                         int bn, int h, int w, int d) {
  const float* Ai = mats + bn * 32;
  const float* M = mats + bn * 32 + 16;
  float u = (float)w * (703.0f / 43.0f);
  float v = (float)h * 17.0f;
  float dep = 2.25f + 0.5f * (float)d;
  float p0 = ((Ai[0] * u + Ai[1] * v) + Ai[2] * dep) + Ai[3];
  float p1 = ((Ai[4] * u + Ai[5] * v) + Ai[6] * dep) + Ai[7];
  float p2 = ((Ai[8] * u + Ai[9] * v) + Ai[10] * dep) + Ai[11];
  float p3 = ((Ai[12] * u + Ai[13] * v) + Ai[14] * dep) + Ai[15];
  float q0 = p0 * p2, q1 = p1 * p2;
  float gx = ((M[0] * q0 + M[1] * q1) + M[2] * p2) + M[3] * p3;
  float gy = ((M[4] * q0 + M[5] * q1) + M[6] * p2) + M[7] * p3;
  float gz = ((M[8] * q0 + M[9] * q1) + M[10] * p2) + M[11] * p3;
  int ix = (int)floorf((gx + 51.2f) / 0.8f);
  int iy = (int)floorf((gy + 51.2f) / 0.8f);
  int iz = (int)floorf((gz + 5.0f) / 8.0f);
  bool valid = (ix >= 0) && (ix < NX_) && (iy >= 0) && (iy < NY_) && (iz == 0);
  int b = bn / N_;
  return valid ? (b * (NY_ * NX_) + iy * NX_ + ix) : -1;
}

// ============================================================================
// Cooperative front-end: memset + prep + transpose + count + scan + fill
// (was 6 graph nodes; now 1 launch with 5 grid syncs, distributed scan)
// ============================================================================
__global__ __launch_bounds__(256, 2) void lss_front(
    const void* __restrict__ ctx, const void* __restrict__ logits,
    const void* __restrict__ s2e, const void* __restrict__ intrin,
    const void* __restrict__ ida, const void* __restrict__ bda,
    float* __restrict__ mats, int* __restrict__ flags,
    int* __restrict__ counts, int* __restrict__ offsets,
    int* __restrict__ cursors, float* __restrict__ ctx_t,
    u16* __restrict__ colids, float* __restrict__ wts,
    int* __restrict__ bsum, int* __restrict__ boff) {
  cg::grid_group grid = cg::this_grid();
  const int t = threadIdx.x;
  const int blk = blockIdx.x;
  const int nblk = gridDim.x;
  const int gtid = blk * 256 + t;
  const int nthr = nblk * 256;
  const int ln = t & 63;
  const int wv = t >> 6;
  const int gw = blk * 4 + wv;   // global wave id
  const int ngw = nblk * 4;      // total waves

  __shared__ float s_w[4][D_];
  __shared__ int s_cell[4][D_];
  __shared__ int s_scan[256];
  __shared__ int s_misc[2];

  // ---------------- P0: zero counts; block 0: dtype detect + matrix fold ----
  for (int i = gtid; i < NCELL; i += nthr) counts[i] = 0;
  if (blk == 0) {
    if (t == 0) s_misc[0] = 0;
    __syncthreads();
    {
      const unsigned short* u = (const unsigned short*)logits;
      unsigned short v = u[2 * t];
      int e = (v >> 7) & 0xFF;
      if (v == 0 || (e >= 110 && e <= 136)) atomicAdd(&s_misc[0], 1);
    }
    __syncthreads();
    if (t == 0) {
      flags[0] = (s_misc[0] > 170) ? 1 : 0;  // tensors bf16?
      float v = ((const float*)intrin)[0];
      s_misc[1] = (v > 100.f && v < 1.0e6f) ? 0 : 1;
      flags[1] = s_misc[1];
    }
    __syncthreads();
    const int mbf = s_misc[1];
    if (t < B_ * N_) {
      int b = t / N_;
      float S[16], I[16], A[16], Bd[16], Iinv[16], Ainv[16], Cm[16], M[16];
      for (int i = 0; i < 16; i++) {
        S[i]  = loadf(s2e,    t * 16 + i, mbf);
        I[i]  = loadf(intrin, t * 16 + i, mbf);
        A[i]  = loadf(ida,    t * 16 + i, mbf);
        Bd[i] = loadf(bda,    b * 16 + i, mbf);
      }
      inv4(I, Iinv);
      inv4(A, Ainv);
      mul4(S, Iinv, Cm);
      mul4(Bd, Cm, M);
      for (int i = 0; i < 16; i++) { mats[t * 32 + i] = Ainv[i]; mats[t * 32 + 16 + i] = M[i]; }
    }
  }
  grid.sync();

  // ---------------- P1: transpose ctx (grid-stride) + count (per wave) ------
  const int tbf = flags[0];
  for (int i = gtid; i < NCOL * C_; i += nthr) {
    int col = i / C_, c = i - col * C_;
    int bn = col / (FH_ * FW_), r = col - bn * (FH_ * FW_);
    int h = r / FW_, w = r - h * FW_;
    ctx_t[i] = loadf(ctx, ((bn * C_ + c) * FH_ + h) * FW_ + w, tbf);
  }
  for (int col = gw; col < NCOL; col += ngw) {
    const int w = col % FW_;
    const int h = (col / FW_) % FH_;
    const int bn = col / (FW_ * FH_);
    int c0 = geom_cell(mats, bn, h, w, ln);
    int c1 = (ln < D_ - 64) ? geom_cell(mats, bn, h, w, ln + 64) : -3;
    int p0 = __shfl_up(c0, 1);          // cell(d-1) for d=ln
    int p1 = __shfl_up(c1, 1);          // cell(d-1) for d=ln+64 (ln>=1)
    int c63 = __shfl(c0, 63);           // cell(63) — predecessor of d=64
    if (ln == 0) p1 = c63;
    if (c0 >= 0 && (ln == 0 || p0 != c0)) atomicAdd(&counts[c0], 1);
    if (c1 >= 0 && p1 != c1) atomicAdd(&counts[c1], 1);
  }
  grid.sync();

  // ---------------- P2a: per-chunk (64-cell) wave scan ----------------------
  for (int cb = gw; cb < NCHUNK; cb += ngw) {
    int c = cb * 64 + ln;
    int v = counts[c];
    int incl = v;
#pragma unroll
    for (int s = 1; s < 64; s <<= 1) {
      int u2 = __shfl_up(incl, s);
      if (ln >= s) incl += u2;
    }
    offsets[c] = incl - v;              // chunk-local exclusive (fixed up in P2c)
    if (ln == 63) bsum[cb] = incl;      // chunk total
  }
  grid.sync();

  // ---------------- P2b: block 0 scans the 512 chunk totals -----------------
  if (blk == 0) {
    int a  = bsum[2 * t];
    int b2 = bsum[2 * t + 1];
    int ps = a + b2;
    s_scan[t] = ps;
    __syncthreads();
    for (int st = 1; st < 256; st <<= 1) {
      int u2 = (t >= st) ? s_scan[t - st] : 0;
      __syncthreads();
      s_scan[t] += u2;
      __syncthreads();
    }
    int base = s_scan[t] - ps;          // exclusive over pairs
    boff[2 * t]     = base;
    boff[2 * t + 1] = base + a;
  }
  grid.sync();

  // ---------------- P2c: fix up global offsets, init cursors ----------------
  for (int i = gtid; i < NCELL; i += nthr) {
    int off = offsets[i] + boff[i >> 6];
    offsets[i] = off;
    cursors[i] = off;
  }
  grid.sync();

  // ---------------- P3: softmax + tuple fill (uniform-trip loop) ------------
  const int ITER = (NCOL + ngw - 1) / ngw;
  for (int it = 0; it < ITER; ++it) {
    const int col = gw + it * ngw;
    const bool act = col < NCOL;
    float inv_sum = 0.f;
    if (act) {
      const int w = col % FW_;
      const int h = (col / FW_) % FH_;
      const int bn = col / (FW_ * FH_);
      const int base = ((bn * D_) * FH_ + h) * FW_ + w;
      float l0 = loadf(logits, base + ln * (FH_ * FW_), tbf);
      float l1 = (ln < D_ - 64) ? loadf(logits, base + (ln + 64) * (FH_ * FW_), tbf) : -1e30f;
      float m = fmaxf(l0, l1);
      for (int s = 32; s > 0; s >>= 1) m = fmaxf(m, __shfl_xor(m, s));
      float e0 = expf(l0 - m);
      float e1 = (ln < D_ - 64) ? expf(l1 - m) : 0.f;
      float sum = e0 + e1;
      for (int s = 32; s > 0; s >>= 1) sum += __shfl_xor(sum, s);
      inv_sum = 1.0f / sum;
      s_w[wv][ln] = e0;
      s_cell[wv][ln] = geom_cell(mats, bn, h, w, ln);
      if (ln < D_ - 64) {
        s_w[wv][ln + 64] = e1;
        s_cell[wv][ln + 64] = geom_cell(mats, bn, h, w, ln + 64);
      }
    }
    __syncthreads();
    if (act) {
      for (int d = ln; d < D_; d += 64) {
        int vcell = s_cell[wv][d];
        if (vcell >= 0 && (d == 0 || s_cell[wv][d - 1] != vcell)) {
          float acc = s_w[wv][d];
          for (int j = d + 1; j < D_ && s_cell[wv][j] == vcell; ++j) acc += s_w[wv][j];
          int pos = atomicAdd(&cursors[vcell], 1);
          colids[pos] = (u16)col;
          wts[pos] = acc * inv_sum;
        }
      }
    }
    __syncthreads();
  }
}

// ---------- gather: one wave per cell; 16 j-slices x 4 channel-quarters ----
__global__ __launch_bounds__(1024) void lss_gather(
    const float* __restrict__ ctx_t, const int* __restrict__ counts,
    const int* __restrict__ offsets, const u16* __restrict__ colids,
    const float* __restrict__ wts, const int* __restrict__ flags,
    void* __restrict__ out) {
  __shared__ float s_out[GB_CELLS * 84];
  const int tid = threadIdx.x;
  const int wv = tid >> 6;          // local cell 0..15
  const int ln = tid & 63;
  const int sl = ln >> 2;           // j-slice 0..15 (lane bits 2..5)
  const int g = ln & 3;             // channel quarter
  const int cell = blockIdx.x * GB_CELLS + wv;
  const int n = counts[cell];
  const int off = offsets[cell];

  float acc[20];
#pragma unroll
  for (int i = 0; i < 20; i++) acc[i] = 0.f;

  for (int j = sl; j < n; j += 16) {
    int colj = colids[off + j];
    float wj = wts[off + j];
    const float4* cp = (const float4*)(ctx_t + colj * C_ + g * 20);
#pragma unroll
    for (int q = 0; q < 5; q++) {
      float4 v = cp[q];
      acc[q * 4 + 0] += wj * v.x;
      acc[q * 4 + 1] += wj * v.y;
      acc[q * 4 + 2] += wj * v.z;
      acc[q * 4 + 3] += wj * v.w;
    }
  }
  // reduce across slice lanes (bits 2..5)
#pragma unroll
  for (int msk = 4; msk <= 32; msk <<= 1) {
#pragma unroll
    for (int i = 0; i < 20; i++) acc[i] += __shfl_xor(acc[i], msk);
  }
  if (sl == 0) {
#pragma unroll
    for (int i = 0; i < 20; i++) s_out[wv * 84 + g * 20 + i] = acc[i];
  }
  __syncthreads();

  // write: x = cell-in-block (16 consecutive yx), c = channel
  const int x = tid & 15;
  const int c0 = tid >> 4;          // 0..63
  const int cell0 = blockIdx.x * GB_CELLS;
  const int b = cell0 >> 14;
  const int yx0 = cell0 & 16383;
  if (flags[0]) {
    bf16* o = (bf16*)out;
    o[(size_t)(b * C_ + c0) * (NY_ * NX_) + yx0 + x] = __float2bfloat16(s_out[x * 84 + c0]);
    if (c0 < 16)
      o[(size_t)(b * C_ + 64 + c0) * (NY_ * NX_) + yx0 + x] = __float2bfloat16(s_out[x * 84 + 64 + c0]);
  } else {
    float* o = (float*)out;
    o[(size_t)(b * C_ + c0) * (NY_ * NX_) + yx0 + x] = s_out[x * 84 + c0];
    if (c0 < 16)
      o[(size_t)(b * C_ + 64 + c0) * (NY_ * NX_) + yx0 + x] = s_out[x * 84 + 64 + c0];
  }
}

extern "C" void kernel_launch(void* const* d_in, const int* in_sizes, int n_in,
                              void* d_out, int out_size, void* d_ws, size_t ws_size,
                              hipStream_t stream) {
  const void* ctx = d_in[0];
  const void* logits = d_in[1];
  const void* s2e = d_in[2];
  const void* intrin = d_in[3];
  const void* ida = d_in[4];
  const void* bda = d_in[5];

  float* wsf = (float*)d_ws;
  int* flags   = (int*)wsf;
  float* mats  = wsf + 16;
  int* counts  = (int*)(wsf + 512);
  int* offsets = (int*)(wsf + 512 + NCELL);
  int* cursors = (int*)(wsf + 512 + 2 * NCELL);
  int* bsum    = (int*)(wsf + 512 + 3 * NCELL);
  int* boff    = bsum + NCHUNK;
  float* ctx_t = wsf + 512 + 3 * NCELL + 2 * NCHUNK;
  u16* colids  = (u16*)(ctx_t + NCOL * C_);
  float* wts   = (float*)((float*)colids + MAXT / 2);

  // co-residency-safe grid size for the cooperative launch (cached)
  static int grid_blocks = 0;
  if (grid_blocks == 0) {
    int nb = 0;
    hipOccupancyMaxActiveBlocksPerMultiprocessor(&nb, (const void*)lss_front, 256, 0);
    if (nb < 1) nb = 1;
    long g = (long)nb * 256;  // 256 CUs on MI355X
    grid_blocks = (int)(g < 512 ? g : 512);
  }

  void* args[16];
  args[0] = (void*)&ctx;     args[1] = (void*)&logits;
  args[2] = (void*)&s2e;     args[3] = (void*)&intrin;
  args[4] = (void*)&ida;     args[5] = (void*)&bda;
  args[6] = (void*)&mats;    args[7] = (void*)&flags;
  args[8] = (void*)&counts;  args[9] = (void*)&offsets;
  args[10] = (void*)&cursors; args[11] = (void*)&ctx_t;
  args[12] = (void*)&colids; args[13] = (void*)&wts;
  args[14] = (void*)&bsum;   args[15] = (void*)&boff;

  hipLaunchCooperativeKernel((void*)lss_front, dim3(grid_blocks), dim3(256),
                             args, 0, stream);
  lss_gather<<<NCELL / GB_CELLS, 1024, 0, stream>>>(ctx_t, counts, offsets,
                                                    colids, wts, flags, d_out);
}